// Round 3
// baseline (325.089 us; speedup 1.0000x reference)
//
#include <hip/hip_runtime.h>
#include <hip/hip_bf16.h>
#include <cstdint>
#include <cstddef>

typedef __bf16 bf16_t;
typedef bf16_t bf16x8 __attribute__((ext_vector_type(8)));
typedef bf16_t bf16x4 __attribute__((ext_vector_type(4)));
typedef float f32x4 __attribute__((ext_vector_type(4)));

#define BN_EPS 1e-5f

// ---- Prep: fold BN + bias into per-column scale/shift; also w1last ---------
__global__ void prep_scales_kernel(const float* W1, const float* b1,
                                   const float* g1, const float* be1, const float* m1,
                                   const float* v1,
                                   const float* g2, const float* be2, const float* m2,
                                   const float* v2, const float* b2,
                                   float* s1, float* t1, float* s2, float* t2,
                                   float* w1last) {
  int i = blockIdx.x * 256 + threadIdx.x;
  if (i < 1024) {
    float s = g1[i] * rsqrtf(v1[i] + BN_EPS);
    s1[i] = s;
    t1[i] = be1[i] - m1[i] * s + b1[i] * s;  // bn(z+b1) = z*s + t
    w1last[i] = W1[256 * 1024 + i];          // conv-feature row of W1 (coalesced)
  }
  if (i < 512) {
    float s = g2[i] * rsqrtf(v2[i] + BN_EPS);
    s2[i] = s;
    t2[i] = be2[i] - m2[i] * s + b2[i] * s;
  }
}

// ---- Coalesced tiled transpose + cast: src[R x C] f32 -> dst[C x R] bf16 ----
__global__ void transpose_cast_kernel(const float* __restrict__ src, bf16_t* __restrict__ dst,
                                      int R, int C) {
  __shared__ bf16_t tile[64][66];  // stride 66: 2-way bank alias = free
  const int r0 = blockIdx.y * 64, c0 = blockIdx.x * 64;
  const int tc = threadIdx.x & 63;
  const int tr4 = threadIdx.x >> 6;  // 0..3
#pragma unroll
  for (int i = 0; i < 16; ++i) {
    int r = i * 4 + tr4;
    tile[r][tc] = (bf16_t)src[(size_t)(r0 + r) * C + c0 + tc];  // coalesced read
  }
  __syncthreads();
#pragma unroll
  for (int i = 0; i < 16; ++i) {
    int rr = i * 4 + tr4;  // dst row within tile (= src col)
    dst[(size_t)(c0 + rr) * R + r0 + tc] = tile[tc][rr];  // coalesced write
  }
}

// ---- Fully fused MLP: x -> h1 (LDS only) -> h2 (regs) -> sigmoid(out) -------
// Block: 64 rows, 512 threads (8 waves) for occupancy (16 waves/CU).
// GEMM1 per chunk: wave w computes 64 rows x 16 cols (cols kc*128+w*16..+16).
// GEMM2: wave w owns output cols [w*64, w*64+64); acc2 = 4x4 f32x4 (64 VGPRs).
__global__ __launch_bounds__(512, 4) void fused_mlp_kernel(
    const float* __restrict__ x,
    const bf16_t* __restrict__ W1T,      // [1024][256]
    const bf16_t* __restrict__ W2T,      // [512][1024]
    const float* __restrict__ s1, const float* __restrict__ t1,
    const float* __restrict__ w1last,
    const float* __restrict__ s2, const float* __restrict__ t2,
    const float* __restrict__ W3, const float* __restrict__ b3,
    float* __restrict__ out) {
  __shared__ __align__(16) bf16_t xs[64 * 264];   // 33.8 KB, 528 B row stride
  __shared__ __align__(16) bf16_t h1s[64 * 136];  // 17.4 KB, 272 B row stride
  __shared__ float convs[64];
  __shared__ float rowsum[64 * 8];

  const int tid = threadIdx.x;
  const int lane = tid & 63;
  const int w = tid >> 6;        // wave 0..7
  const int l15 = lane & 15;
  const int quad = lane >> 4;
  const int row0 = blockIdx.x * 64;

  // ---- Stage x (fp32 -> bf16) into LDS + per-row conv feature ----
#pragma unroll
  for (int it = 0; it < 8; ++it) {
    int r = it * 8 + w;
    const float4 v = *(const float4*)(x + (size_t)(row0 + r) * 256 + lane * 4);
    float s = v.x + v.y + v.z + v.w;
    bf16x4 o = {(bf16_t)v.x, (bf16_t)v.y, (bf16_t)v.z, (bf16_t)v.w};
    *(bf16x4*)(xs + r * 264 + lane * 4) = o;
#pragma unroll
    for (int off = 32; off >= 1; off >>= 1) s += __shfl_down(s, off);
    if (lane == 0) convs[r] = (s > 0.0f) ? 1.0f : 0.0f;  // mean>0 <=> sum>0
  }
  __syncthreads();

  f32x4 acc2[4][4];
#pragma unroll
  for (int i = 0; i < 4; ++i)
#pragma unroll
    for (int j = 0; j < 4; ++j) {
      f32x4 z = {0.f, 0.f, 0.f, 0.f};
      acc2[i][j] = z;
    }

  const bf16_t* W2b = W2T + (size_t)(w * 64) * 1024;

  for (int kc = 0; kc < 8; ++kc) {
    // ---- GEMM1 chunk: 64 rows x 16 cols (this wave), K=256 ----
    const int colbase = kc * 128 + w * 16;
    const bf16_t* Wb = W1T + (size_t)colbase * 256;
    bf16x8 bfr[8];
#pragma unroll
    for (int ks = 0; ks < 8; ++ks)
      bfr[ks] = *(const bf16x8*)(Wb + (size_t)l15 * 256 + ks * 32 + quad * 8);
    f32x4 acc1[4];
#pragma unroll
    for (int i = 0; i < 4; ++i) {
      f32x4 z = {0.f, 0.f, 0.f, 0.f};
      acc1[i] = z;
    }
#pragma unroll
    for (int ks = 0; ks < 8; ++ks) {
#pragma unroll
      for (int ti = 0; ti < 4; ++ti) {
        bf16x8 af = *(const bf16x8*)(xs + (ti * 16 + l15) * 264 + ks * 32 + quad * 8);
        acc1[ti] = __builtin_amdgcn_mfma_f32_16x16x32_bf16(af, bfr[ks], acc1[ti], 0, 0, 0);
      }
    }
    // ---- epilogue: conv rank-1 + BN1 + ReLU -> h1s (bf16) ----
    const int c = colbase + l15;
    const float s1c = s1[c], t1c = t1[c], wlc = w1last[c];
    __syncthreads();  // previous chunk's GEMM2 reads of h1s complete
#pragma unroll
    for (int ti = 0; ti < 4; ++ti)
#pragma unroll
      for (int r = 0; r < 4; ++r) {
        int rr = ti * 16 + quad * 4 + r;
        float z = acc1[ti][r] + convs[rr] * wlc;
        z = fmaxf(z * s1c + t1c, 0.f);
        h1s[rr * 136 + w * 16 + l15] = (bf16_t)z;
      }
    __syncthreads();
    // ---- GEMM2 accumulate: acc2 += h1s(64x128) @ W2T[w*64..+64][kc*128..+128]^T
#pragma unroll
    for (int k2 = 0; k2 < 4; ++k2) {
      bf16x8 af2[4];
#pragma unroll
      for (int ti = 0; ti < 4; ++ti)
        af2[ti] = *(const bf16x8*)(h1s + (ti * 16 + l15) * 136 + k2 * 32 + quad * 8);
#pragma unroll
      for (int tj = 0; tj < 4; ++tj) {
        bf16x8 b2r = *(const bf16x8*)(W2b + (size_t)(tj * 16 + l15) * 1024 + kc * 128 + k2 * 32 + quad * 8);
#pragma unroll
        for (int ti = 0; ti < 4; ++ti)
          acc2[ti][tj] = __builtin_amdgcn_mfma_f32_16x16x32_bf16(af2[ti], b2r, acc2[ti][tj], 0, 0, 0);
      }
    }
  }

  // ---- Final: BN2 + ReLU + dot(W3) + sigmoid ----
  float s2c[4], t2c[4], w3c[4];
#pragma unroll
  for (int tj = 0; tj < 4; ++tj) {
    int c = w * 64 + tj * 16 + l15;
    s2c[tj] = s2[c];
    t2c[tj] = t2[c];
    w3c[tj] = W3[c];
  }
#pragma unroll
  for (int ti = 0; ti < 4; ++ti)
#pragma unroll
    for (int r = 0; r < 4; ++r) {
      float p = 0.f;
#pragma unroll
      for (int tj = 0; tj < 4; ++tj) {
        float z = fmaxf(acc2[ti][tj][r] * s2c[tj] + t2c[tj], 0.f);
        p += z * w3c[tj];
      }
      // reduce across the 16 l15 lanes (masks 1..8 stay within the group)
#pragma unroll
      for (int m = 1; m <= 8; m <<= 1) p += __shfl_xor(p, m);
      if (l15 == 0) rowsum[(ti * 16 + quad * 4 + r) * 8 + w] = p;
    }
  __syncthreads();
  if (tid < 64) {
    float z = b3[0];
#pragma unroll
    for (int j = 0; j < 8; ++j) z += rowsum[tid * 8 + j];
    out[row0 + tid] = 1.0f / (1.0f + expf(-z));
  }
}

extern "C" void kernel_launch(void* const* d_in, const int* in_sizes, int n_in,
                              void* d_out, int out_size, void* d_ws, size_t ws_size,
                              hipStream_t stream) {
  const float* x = (const float*)d_in[0];
  const float* W1 = (const float*)d_in[1];
  const float* b1 = (const float*)d_in[2];
  const float* g1 = (const float*)d_in[3];
  const float* be1 = (const float*)d_in[4];
  const float* m1 = (const float*)d_in[5];
  const float* v1 = (const float*)d_in[6];
  const float* W2 = (const float*)d_in[7];
  const float* b2 = (const float*)d_in[8];
  const float* g2 = (const float*)d_in[9];
  const float* be2 = (const float*)d_in[10];
  const float* m2 = (const float*)d_in[11];
  const float* v2 = (const float*)d_in[12];
  const float* W3 = (const float*)d_in[13];
  const float* b3 = (const float*)d_in[14];
  float* out = (float*)d_out;

  char* p = (char*)d_ws;
  bf16_t* W1T = (bf16_t*)p;   p += (size_t)1024 * 256 * 2;
  bf16_t* W2T = (bf16_t*)p;   p += (size_t)512 * 1024 * 2;
  float* w1last = (float*)p;  p += 1024 * 4;
  float* s1 = (float*)p;      p += 1024 * 4;
  float* t1 = (float*)p;      p += 1024 * 4;
  float* s2 = (float*)p;      p += 512 * 4;
  float* t2 = (float*)p;      p += 512 * 4;

  prep_scales_kernel<<<4, 256, 0, stream>>>(W1, b1, g1, be1, m1, v1,
                                            g2, be2, m2, v2, b2,
                                            s1, t1, s2, t2, w1last);
  // W1 rows 0..255 -> W1T [1024][256]
  transpose_cast_kernel<<<dim3(16, 4), 256, 0, stream>>>(W1, W1T, 256, 1024);
  // W2 [1024][512] -> W2T [512][1024]
  transpose_cast_kernel<<<dim3(8, 16), 256, 0, stream>>>(W2, W2T, 1024, 512);

  fused_mlp_kernel<<<1024, 512, 0, stream>>>(x, W1T, W2T, s1, t1, w1last, s2, t2, W3, b3, out);
}

// Round 4
// 323.855 us; speedup vs baseline: 1.0038x; 1.0038x over previous
//
#include <hip/hip_runtime.h>
#include <hip/hip_bf16.h>
#include <cstdint>
#include <cstddef>

typedef __bf16 bf16_t;
typedef bf16_t bf16x8 __attribute__((ext_vector_type(8)));
typedef bf16_t bf16x4 __attribute__((ext_vector_type(4)));
typedef float f32x4 __attribute__((ext_vector_type(4)));

#define BN_EPS 1e-5f

// ---- Prep: fold BN + bias into per-column scale/shift; also w1last ---------
__global__ void prep_scales_kernel(const float* W1, const float* b1,
                                   const float* g1, const float* be1, const float* m1,
                                   const float* v1,
                                   const float* g2, const float* be2, const float* m2,
                                   const float* v2, const float* b2,
                                   float* s1, float* t1, float* s2, float* t2,
                                   float* w1last) {
  int i = blockIdx.x * 256 + threadIdx.x;
  if (i < 1024) {
    float s = g1[i] * rsqrtf(v1[i] + BN_EPS);
    s1[i] = s;
    t1[i] = be1[i] - m1[i] * s + b1[i] * s;  // bn(z+b1) = z*s + t
    w1last[i] = W1[256 * 1024 + i];          // conv-feature row of W1 (coalesced)
  }
  if (i < 512) {
    float s = g2[i] * rsqrtf(v2[i] + BN_EPS);
    s2[i] = s;
    t2[i] = be2[i] - m2[i] * s + b2[i] * s;
  }
}

// ---- Coalesced tiled transpose + cast: W1[256+1 x 1024] -> W1T[1024][256] ---
__global__ void transpose_cast_kernel(const float* __restrict__ src, bf16_t* __restrict__ dst,
                                      int R, int C) {
  __shared__ bf16_t tile[64][66];
  const int r0 = blockIdx.y * 64, c0 = blockIdx.x * 64;
  const int tc = threadIdx.x & 63;
  const int tr4 = threadIdx.x >> 6;
#pragma unroll
  for (int i = 0; i < 16; ++i) {
    int r = i * 4 + tr4;
    tile[r][tc] = (bf16_t)src[(size_t)(r0 + r) * C + c0 + tc];  // coalesced read
  }
  __syncthreads();
#pragma unroll
  for (int i = 0; i < 16; ++i) {
    int rr = i * 4 + tr4;
    dst[(size_t)(c0 + rr) * R + r0 + tc] = tile[tc][rr];  // coalesced write
  }
}

// ---- W2[1024][512] f32 -> W2C[kc][512][128] bf16 (chunk-major, K-contig) ----
// W2C[((kc*512)+n)*128 + kk] = W2[(kc*128+kk)*512 + n]
__global__ void prep_w2c_kernel(const float* __restrict__ W2, bf16_t* __restrict__ W2C) {
  __shared__ bf16_t tile[64][66];
  const int k0 = blockIdx.y * 64;  // k tile base (0..1023, 16 tiles)
  const int n0 = blockIdx.x * 64;  // n tile base (0..511, 8 tiles)
  const int tc = threadIdx.x & 63;
  const int tr4 = threadIdx.x >> 6;
  const int kc = k0 >> 7;          // chunk index
  const int kk0 = k0 & 127;        // k offset within chunk (0 or 64)
#pragma unroll
  for (int i = 0; i < 16; ++i) {
    int k = i * 4 + tr4;
    tile[k][tc] = (bf16_t)W2[(size_t)(k0 + k) * 512 + n0 + tc];  // coalesced read
  }
  __syncthreads();
#pragma unroll
  for (int i = 0; i < 16; ++i) {
    int nn = i * 4 + tr4;  // n within tile
    // row (n0+nn) of chunk kc, k-cols kk0..kk0+63; tc contiguous => coalesced
    W2C[((size_t)kc * 512 + n0 + nn) * 128 + kk0 + tc] = tile[tc][nn];
  }
}

// ---- Fully fused MLP: x -> h1 (LDS only) -> h2 (regs) -> sigmoid(out) -------
// Block: 64 rows, 256 threads (4 waves). r2 shape (no spills) + chunk stagger.
// GEMM1 per chunk: wave w computes 64 rows x 32 cols.
// GEMM2: wave w owns output cols [w*128, w*128+128); acc2 = 32 f32x4 (AGPR).
// Chunk order staggered by blockIdx.x so co-resident blocks hit different
// weight regions in L2 (de-storm).
__global__ __launch_bounds__(256, 2) void fused_mlp_kernel(
    const float* __restrict__ x,
    const bf16_t* __restrict__ W1T,      // [1024][256]
    const bf16_t* __restrict__ W2C,      // [8][512][128] chunk-major
    const float* __restrict__ s1, const float* __restrict__ t1,
    const float* __restrict__ w1last,
    const float* __restrict__ s2, const float* __restrict__ t2,
    const float* __restrict__ W3, const float* __restrict__ b3,
    float* __restrict__ out) {
  __shared__ __align__(16) bf16_t xs[64 * 264];
  __shared__ __align__(16) bf16_t h1s[64 * 136];
  __shared__ float convs[64];
  __shared__ float rowsum[64 * 4];

  const int tid = threadIdx.x;
  const int lane = tid & 63;
  const int w = tid >> 6;
  const int l15 = lane & 15;
  const int quad = lane >> 4;
  const int row0 = blockIdx.x * 64;

  // ---- Stage x (fp32 -> bf16) into LDS + per-row conv feature ----
#pragma unroll
  for (int it = 0; it < 16; ++it) {
    int r = it * 4 + w;
    const float4 v = *(const float4*)(x + (size_t)(row0 + r) * 256 + lane * 4);
    float s = v.x + v.y + v.z + v.w;
    bf16x4 o = {(bf16_t)v.x, (bf16_t)v.y, (bf16_t)v.z, (bf16_t)v.w};
    *(bf16x4*)(xs + r * 264 + lane * 4) = o;
#pragma unroll
    for (int off = 32; off >= 1; off >>= 1) s += __shfl_down(s, off);
    if (lane == 0) convs[r] = (s > 0.0f) ? 1.0f : 0.0f;  // mean>0 <=> sum>0
  }
  __syncthreads();

  f32x4 acc2[4][8];
#pragma unroll
  for (int i = 0; i < 4; ++i)
#pragma unroll
    for (int j = 0; j < 8; ++j) {
      f32x4 z = {0.f, 0.f, 0.f, 0.f};
      acc2[i][j] = z;
    }

  for (int kci = 0; kci < 8; ++kci) {
    const int kc = (kci + blockIdx.x) & 7;  // staggered chunk order
    // ---- GEMM1 chunk: 64 rows x 32 cols (this wave), K=256 ----
    const int colbase = kc * 128 + w * 32;
    const bf16_t* Wb = W1T + (size_t)colbase * 256;
    f32x4 acc1[4][2];
#pragma unroll
    for (int i = 0; i < 4; ++i)
#pragma unroll
      for (int j = 0; j < 2; ++j) {
        f32x4 z = {0.f, 0.f, 0.f, 0.f};
        acc1[i][j] = z;
      }
#pragma unroll
    for (int ks = 0; ks < 8; ++ks) {
      bf16x8 af[4];
#pragma unroll
      for (int ti = 0; ti < 4; ++ti)
        af[ti] = *(const bf16x8*)(xs + (ti * 16 + l15) * 264 + ks * 32 + quad * 8);
#pragma unroll
      for (int tj = 0; tj < 2; ++tj) {
        bf16x8 bfr = *(const bf16x8*)(Wb + (size_t)(tj * 16 + l15) * 256 + ks * 32 + quad * 8);
#pragma unroll
        for (int ti = 0; ti < 4; ++ti)
          acc1[ti][tj] = __builtin_amdgcn_mfma_f32_16x16x32_bf16(af[ti], bfr, acc1[ti][tj], 0, 0, 0);
      }
    }
    // guard: previous chunk's GEMM2 reads of h1s must complete before overwrite
    __syncthreads();
    // ---- epilogue: conv rank-1 + BN1 + ReLU -> h1s (bf16) ----
    float s1c[2], t1c[2], wlc[2];
#pragma unroll
    for (int tj = 0; tj < 2; ++tj) {
      int c = colbase + tj * 16 + l15;
      s1c[tj] = s1[c];
      t1c[tj] = t1[c];
      wlc[tj] = w1last[c];
    }
#pragma unroll
    for (int ti = 0; ti < 4; ++ti)
#pragma unroll
      for (int r = 0; r < 4; ++r) {
        int rr = ti * 16 + quad * 4 + r;
        float cf = convs[rr];
#pragma unroll
        for (int tj = 0; tj < 2; ++tj) {
          float z = acc1[ti][tj][r] + cf * wlc[tj];
          z = fmaxf(z * s1c[tj] + t1c[tj], 0.f);
          h1s[rr * 136 + w * 32 + tj * 16 + l15] = (bf16_t)z;
        }
      }
    __syncthreads();
    // ---- GEMM2 accumulate: acc2 += h1s(64x128) @ W2C[kc][w*128..+128][:]^T
    const bf16_t* W2b = W2C + ((size_t)kc * 512 + w * 128) * 128;
#pragma unroll
    for (int k2 = 0; k2 < 4; ++k2) {
      bf16x8 af2[4];
#pragma unroll
      for (int ti = 0; ti < 4; ++ti)
        af2[ti] = *(const bf16x8*)(h1s + (ti * 16 + l15) * 136 + k2 * 32 + quad * 8);
#pragma unroll
      for (int tj = 0; tj < 8; ++tj) {
        bf16x8 b2r = *(const bf16x8*)(W2b + (size_t)(tj * 16 + l15) * 128 + k2 * 32 + quad * 8);
#pragma unroll
        for (int ti = 0; ti < 4; ++ti)
          acc2[ti][tj] = __builtin_amdgcn_mfma_f32_16x16x32_bf16(af2[ti], b2r, acc2[ti][tj], 0, 0, 0);
      }
    }
  }

  // ---- Final: BN2 + ReLU + dot(W3) + sigmoid ----
  float s2c[8], t2c[8], w3c[8];
#pragma unroll
  for (int tj = 0; tj < 8; ++tj) {
    int c = w * 128 + tj * 16 + l15;
    s2c[tj] = s2[c];
    t2c[tj] = t2[c];
    w3c[tj] = W3[c];
  }
#pragma unroll
  for (int ti = 0; ti < 4; ++ti)
#pragma unroll
    for (int r = 0; r < 4; ++r) {
      float p = 0.f;
#pragma unroll
      for (int tj = 0; tj < 8; ++tj) {
        float z = fmaxf(acc2[ti][tj][r] * s2c[tj] + t2c[tj], 0.f);
        p += z * w3c[tj];
      }
      // reduce across the 16 l15 lanes
#pragma unroll
      for (int m = 1; m <= 8; m <<= 1) p += __shfl_xor(p, m);
      if (l15 == 0) rowsum[(ti * 16 + quad * 4 + r) * 4 + w] = p;
    }
  __syncthreads();
  if (tid < 64) {
    float z = b3[0] + rowsum[tid * 4] + rowsum[tid * 4 + 1] + rowsum[tid * 4 + 2] + rowsum[tid * 4 + 3];
    out[row0 + tid] = 1.0f / (1.0f + expf(-z));
  }
}

extern "C" void kernel_launch(void* const* d_in, const int* in_sizes, int n_in,
                              void* d_out, int out_size, void* d_ws, size_t ws_size,
                              hipStream_t stream) {
  const float* x = (const float*)d_in[0];
  const float* W1 = (const float*)d_in[1];
  const float* b1 = (const float*)d_in[2];
  const float* g1 = (const float*)d_in[3];
  const float* be1 = (const float*)d_in[4];
  const float* m1 = (const float*)d_in[5];
  const float* v1 = (const float*)d_in[6];
  const float* W2 = (const float*)d_in[7];
  const float* b2 = (const float*)d_in[8];
  const float* g2 = (const float*)d_in[9];
  const float* be2 = (const float*)d_in[10];
  const float* m2 = (const float*)d_in[11];
  const float* v2 = (const float*)d_in[12];
  const float* W3 = (const float*)d_in[13];
  const float* b3 = (const float*)d_in[14];
  float* out = (float*)d_out;

  char* p = (char*)d_ws;
  bf16_t* W1T = (bf16_t*)p;   p += (size_t)1024 * 256 * 2;
  bf16_t* W2C = (bf16_t*)p;   p += (size_t)512 * 1024 * 2;
  float* w1last = (float*)p;  p += 1024 * 4;
  float* s1 = (float*)p;      p += 1024 * 4;
  float* t1 = (float*)p;      p += 1024 * 4;
  float* s2 = (float*)p;      p += 512 * 4;
  float* t2 = (float*)p;      p += 512 * 4;

  prep_scales_kernel<<<4, 256, 0, stream>>>(W1, b1, g1, be1, m1, v1,
                                            g2, be2, m2, v2, b2,
                                            s1, t1, s2, t2, w1last);
  // W1 rows 0..255 -> W1T [1024][256]
  transpose_cast_kernel<<<dim3(16, 4), 256, 0, stream>>>(W1, W1T, 256, 1024);
  // W2 [1024][512] -> W2C [8][512][128] chunk-major
  prep_w2c_kernel<<<dim3(8, 16), 256, 0, stream>>>(W2, W2C);

  fused_mlp_kernel<<<1024, 256, 0, stream>>>(x, W1T, W2C, s1, t1, w1last, s2, t2, W3, b3, out);
}

// Round 5
// 292.387 us; speedup vs baseline: 1.1118x; 1.1076x over previous
//
#include <hip/hip_runtime.h>
#include <hip/hip_bf16.h>
#include <cstdint>
#include <cstddef>

typedef __bf16 bf16_t;
typedef bf16_t bf16x8 __attribute__((ext_vector_type(8)));
typedef bf16_t bf16x4 __attribute__((ext_vector_type(4)));
typedef float f32x4 __attribute__((ext_vector_type(4)));

#define BN_EPS 1e-5f

// Async global->LDS, 16B per lane (wave-uniform LDS base; lane i -> base+i*16).
__device__ __forceinline__ void async_load16(const bf16_t* g, bf16_t* lds) {
  __builtin_amdgcn_global_load_lds(
      (__attribute__((address_space(1))) uint32_t*)(g),
      (__attribute__((address_space(3))) uint32_t*)(lds),
      16, 0, 0);
}

// ---- Merged prep: W1 transpose (blocks 0-63), W2 transpose (64-191),
// ---- BN fold + w1last (192-195). One dispatch instead of three.
__global__ void prep_all_kernel(const float* __restrict__ W1, const float* __restrict__ W2,
                                const float* b1, const float* g1, const float* be1,
                                const float* m1, const float* v1,
                                const float* b2, const float* g2, const float* be2,
                                const float* m2, const float* v2,
                                bf16_t* __restrict__ W1T, bf16_t* __restrict__ W2T,
                                float* s1, float* t1, float* s2, float* t2,
                                float* w1last) {
  const int b = blockIdx.x;
  if (b < 192) {
    // tiled transpose+cast: src[R x C] f32 -> dst[C x R] bf16
    const float* src;
    bf16_t* dst;
    int R, C, bx, by;
    if (b < 64) { src = W1; dst = W1T; R = 256; C = 1024; bx = b & 15; by = b >> 4; }
    else        { src = W2; dst = W2T; R = 1024; C = 512; bx = (b - 64) & 7; by = (b - 64) >> 3; }
    __shared__ bf16_t tile[64][66];
    const int r0 = by * 64, c0 = bx * 64;
    const int tc = threadIdx.x & 63;
    const int tr4 = threadIdx.x >> 6;
#pragma unroll
    for (int i = 0; i < 16; ++i) {
      int r = i * 4 + tr4;
      tile[r][tc] = (bf16_t)src[(size_t)(r0 + r) * C + c0 + tc];  // coalesced read
    }
    __syncthreads();
#pragma unroll
    for (int i = 0; i < 16; ++i) {
      int rr = i * 4 + tr4;
      dst[(size_t)(c0 + rr) * R + r0 + tc] = tile[tc][rr];  // coalesced write
    }
  } else {
    int i = (b - 192) * 256 + threadIdx.x;
    if (i < 1024) {
      float s = g1[i] * rsqrtf(v1[i] + BN_EPS);
      s1[i] = s;
      t1[i] = be1[i] - m1[i] * s + b1[i] * s;  // bn(z+b1) = z*s + t
      w1last[i] = W1[256 * 1024 + i];          // conv-feature row (coalesced)
    }
    if (i < 512) {
      float s = g2[i] * rsqrtf(v2[i] + BN_EPS);
      s2[i] = s;
      t2[i] = be2[i] - m2[i] * s + b2[i] * s;
    }
  }
}

// ---- Prep: x -> bf16 + conv feature (mean>0); also zero the logit accum ----
__global__ void prep_x_kernel(const float* __restrict__ x, bf16_t* __restrict__ xb,
                              float* __restrict__ convf, float* __restrict__ outacc) {
  int lane = threadIdx.x & 63;
  int w = threadIdx.x >> 6;
  int row = blockIdx.x * 4 + w;
  const float4 v = *(const float4*)(x + (size_t)row * 256 + lane * 4);
  float s = v.x + v.y + v.z + v.w;
  bf16x4 o = {(bf16_t)v.x, (bf16_t)v.y, (bf16_t)v.z, (bf16_t)v.w};
  *(bf16x4*)(xb + (size_t)row * 256 + lane * 4) = o;
#pragma unroll
  for (int off = 32; off >= 1; off >>= 1) s += __shfl_down(s, off);
  if (lane == 0) convf[row] = (s > 0.0f) ? 1.0f : 0.0f;  // mean>0 <=> sum>0
  if (threadIdx.x < 4) outacc[blockIdx.x * 4 + threadIdx.x] = 0.0f;
}

// ---- GEMM1: h1 = relu(bn1(xb @ W1T^T + conv rank-1)), bf16 out --------------
// r1-proven structure: 128x128 tile, 4 waves x (4x4 of 16x16x32), BK=32.
__global__ __launch_bounds__(256) void gemm1_kernel(
    const bf16_t* __restrict__ A, const bf16_t* __restrict__ BT,
    const float* __restrict__ sN, const float* __restrict__ tN,
    const float* __restrict__ convf, const float* __restrict__ w1last,
    bf16_t* __restrict__ out) {
  constexpr int K = 256, N = 1024;
  __shared__ __align__(16) bf16_t As[128 * 32];
  __shared__ __align__(16) bf16_t Bs[128 * 32];

  const int tid = threadIdx.x;
  const int lane = tid & 63;
  const int w = tid >> 6;
  const int l15 = lane & 15;
  const int quad = lane >> 4;
  const int wm = (w >> 1) * 64;
  const int wn = (w & 1) * 64;
  const int mTile = blockIdx.y * 128;
  const int nTile = blockIdx.x * 128;

  const int sRow = lane >> 2;
  const int sCol = (lane & 3) * 8;
  const bf16_t* gA = A + (size_t)(mTile + w * 32 + sRow) * K + sCol;
  const bf16_t* gB = BT + (size_t)(nTile + w * 32 + sRow) * K + sCol;
  bf16_t* lA = As + (w * 32) * 32;
  bf16_t* lB = Bs + (w * 32) * 32;

  f32x4 acc[4][4];
#pragma unroll
  for (int i = 0; i < 4; ++i)
#pragma unroll
    for (int j = 0; j < 4; ++j) {
      f32x4 z = {0.f, 0.f, 0.f, 0.f};
      acc[i][j] = z;
    }

  for (int k0 = 0; k0 < K; k0 += 32) {
    async_load16(gA + k0, lA);
    async_load16(gA + (size_t)16 * K + k0, lA + 16 * 32);
    async_load16(gB + k0, lB);
    async_load16(gB + (size_t)16 * K + k0, lB + 16 * 32);
    __syncthreads();

    bf16x8 af[4], bfr[4];
#pragma unroll
    for (int t = 0; t < 4; ++t) {
      af[t] = *(const bf16x8*)(As + (wm + t * 16 + l15) * 32 + quad * 8);
      bfr[t] = *(const bf16x8*)(Bs + (wn + t * 16 + l15) * 32 + quad * 8);
    }
#pragma unroll
    for (int ti = 0; ti < 4; ++ti)
#pragma unroll
      for (int tj = 0; tj < 4; ++tj)
        acc[ti][tj] = __builtin_amdgcn_mfma_f32_16x16x32_bf16(af[ti], bfr[tj], acc[ti][tj], 0, 0, 0);
    __syncthreads();
  }

  // Epilogue: conv rank-1 + BN1 + ReLU -> bf16. C/D: col=lane&15, row=quad*4+reg.
  float sc[4], tc[4], wl[4];
#pragma unroll
  for (int tj = 0; tj < 4; ++tj) {
    int c = nTile + wn + tj * 16 + l15;
    sc[tj] = sN[c];
    tc[tj] = tN[c];
    wl[tj] = w1last[c];
  }
#pragma unroll
  for (int ti = 0; ti < 4; ++ti)
#pragma unroll
    for (int r = 0; r < 4; ++r) {
      int row = mTile + wm + ti * 16 + quad * 4 + r;
      float cf = convf[row];
      size_t base = (size_t)row * N + nTile + wn;
#pragma unroll
      for (int tj = 0; tj < 4; ++tj) {
        float z = acc[ti][tj][r] + cf * wl[tj];
        z = fmaxf(z * sc[tj] + tc[tj], 0.f);
        out[base + tj * 16 + l15] = (bf16_t)z;
      }
    }
}

// ---- GEMM2 + head: partial logits via atomicAdd into outacc -----------------
// Same GEMM core; epilogue computes sum_cols relu(bn2(z))*W3 per row and
// atomically accumulates. Grid: 2048 linear, swizzled so the 4 N-blocks of
// an M-tile land in one group of 8 consecutive blocks (h1 L2/L3 reuse).
__global__ __launch_bounds__(256) void gemm2_head_kernel(
    const bf16_t* __restrict__ A, const bf16_t* __restrict__ BT,
    const float* __restrict__ sN, const float* __restrict__ tN,
    const float* __restrict__ W3, float* __restrict__ outacc) {
  constexpr int K = 1024;
  __shared__ __align__(16) bf16_t As[128 * 32];
  __shared__ __align__(16) bf16_t Bs[128 * 32];
  __shared__ float rowsum[128][2];

  const int b = blockIdx.x;
  const int group = b >> 3;
  const int mTile = (group * 2 + (b & 1)) * 128;   // 512 M-tiles
  const int nTile = ((b >> 1) & 3) * 128;          // 4 N-tiles

  const int tid = threadIdx.x;
  const int lane = tid & 63;
  const int w = tid >> 6;
  const int l15 = lane & 15;
  const int quad = lane >> 4;
  const int wm = (w >> 1) * 64;
  const int wn = (w & 1) * 64;

  const int sRow = lane >> 2;
  const int sCol = (lane & 3) * 8;
  const bf16_t* gA = A + (size_t)(mTile + w * 32 + sRow) * K + sCol;
  const bf16_t* gB = BT + (size_t)(nTile + w * 32 + sRow) * K + sCol;
  bf16_t* lA = As + (w * 32) * 32;
  bf16_t* lB = Bs + (w * 32) * 32;

  f32x4 acc[4][4];
#pragma unroll
  for (int i = 0; i < 4; ++i)
#pragma unroll
    for (int j = 0; j < 4; ++j) {
      f32x4 z = {0.f, 0.f, 0.f, 0.f};
      acc[i][j] = z;
    }

  for (int k0 = 0; k0 < K; k0 += 32) {
    async_load16(gA + k0, lA);
    async_load16(gA + (size_t)16 * K + k0, lA + 16 * 32);
    async_load16(gB + k0, lB);
    async_load16(gB + (size_t)16 * K + k0, lB + 16 * 32);
    __syncthreads();

    bf16x8 af[4], bfr[4];
#pragma unroll
    for (int t = 0; t < 4; ++t) {
      af[t] = *(const bf16x8*)(As + (wm + t * 16 + l15) * 32 + quad * 8);
      bfr[t] = *(const bf16x8*)(Bs + (wn + t * 16 + l15) * 32 + quad * 8);
    }
#pragma unroll
    for (int ti = 0; ti < 4; ++ti)
#pragma unroll
      for (int tj = 0; tj < 4; ++tj)
        acc[ti][tj] = __builtin_amdgcn_mfma_f32_16x16x32_bf16(af[ti], bfr[tj], acc[ti][tj], 0, 0, 0);
    __syncthreads();
  }

  // Epilogue: per-row partial of relu(bn2)*W3 over this block's 128 cols.
  float sc[4], tc[4], w3c[4];
#pragma unroll
  for (int tj = 0; tj < 4; ++tj) {
    int c = nTile + wn + tj * 16 + l15;
    sc[tj] = sN[c];
    tc[tj] = tN[c];
    w3c[tj] = W3[c];
  }
#pragma unroll
  for (int ti = 0; ti < 4; ++ti)
#pragma unroll
    for (int r = 0; r < 4; ++r) {
      float p = 0.f;
#pragma unroll
      for (int tj = 0; tj < 4; ++tj) {
        float z = fmaxf(acc[ti][tj][r] * sc[tj] + tc[tj], 0.f);
        p += z * w3c[tj];
      }
#pragma unroll
      for (int m = 1; m <= 8; m <<= 1) p += __shfl_xor(p, m);  // reduce 16 cols-lanes
      if (l15 == 0) rowsum[wm + ti * 16 + quad * 4 + r][wn >> 6] = p;
    }
  __syncthreads();
  if (tid < 128) atomicAdd(outacc + mTile + tid, rowsum[tid][0] + rowsum[tid][1]);
}

// ---- Final sigmoid over accumulated logits ----------------------------------
__global__ void sigmoid_kernel(float* __restrict__ out, const float* __restrict__ b3) {
  int i = blockIdx.x * 256 + threadIdx.x;
  float z = out[i] + b3[0];
  out[i] = 1.0f / (1.0f + expf(-z));
}

extern "C" void kernel_launch(void* const* d_in, const int* in_sizes, int n_in,
                              void* d_out, int out_size, void* d_ws, size_t ws_size,
                              hipStream_t stream) {
  const float* x = (const float*)d_in[0];
  const float* W1 = (const float*)d_in[1];
  const float* b1 = (const float*)d_in[2];
  const float* g1 = (const float*)d_in[3];
  const float* be1 = (const float*)d_in[4];
  const float* m1 = (const float*)d_in[5];
  const float* v1 = (const float*)d_in[6];
  const float* W2 = (const float*)d_in[7];
  const float* b2 = (const float*)d_in[8];
  const float* g2 = (const float*)d_in[9];
  const float* be2 = (const float*)d_in[10];
  const float* m2 = (const float*)d_in[11];
  const float* v2 = (const float*)d_in[12];
  const float* W3 = (const float*)d_in[13];
  const float* b3 = (const float*)d_in[14];
  float* out = (float*)d_out;  // doubles as the fp32 logit accumulator

  char* p = (char*)d_ws;
  bf16_t* h1 = (bf16_t*)p;    p += (size_t)65536 * 1024 * 2;  // 128 MB
  bf16_t* xb = (bf16_t*)p;    p += (size_t)65536 * 256 * 2;   // 32 MB
  bf16_t* W1T = (bf16_t*)p;   p += (size_t)1024 * 256 * 2;
  bf16_t* W2T = (bf16_t*)p;   p += (size_t)512 * 1024 * 2;
  float* convf = (float*)p;   p += (size_t)65536 * 4;
  float* w1last = (float*)p;  p += 1024 * 4;
  float* s1 = (float*)p;      p += 1024 * 4;
  float* t1 = (float*)p;      p += 1024 * 4;
  float* s2 = (float*)p;      p += 512 * 4;
  float* t2 = (float*)p;      p += 512 * 4;

  prep_all_kernel<<<196, 256, 0, stream>>>(W1, W2, b1, g1, be1, m1, v1,
                                           b2, g2, be2, m2, v2,
                                           W1T, W2T, s1, t1, s2, t2, w1last);
  prep_x_kernel<<<16384, 256, 0, stream>>>(x, xb, convf, out);

  gemm1_kernel<<<dim3(8, 512), 256, 0, stream>>>(xb, W1T, s1, t1, convf, w1last, h1);
  gemm2_head_kernel<<<2048, 256, 0, stream>>>(h1, W2T, s2, t2, W3, out);

  sigmoid_kernel<<<256, 256, 0, stream>>>(out, b3);
}

// Round 6
// 256.505 us; speedup vs baseline: 1.2674x; 1.1399x over previous
//
#include <hip/hip_runtime.h>
#include <hip/hip_bf16.h>
#include <cstdint>
#include <cstddef>

typedef __bf16 bf16_t;
typedef bf16_t bf16x8 __attribute__((ext_vector_type(8)));
typedef bf16_t bf16x4 __attribute__((ext_vector_type(4)));
typedef float f32x4 __attribute__((ext_vector_type(4)));

#define BN_EPS 1e-5f

// Async global->LDS, 16B per lane (wave-uniform LDS base; lane i -> base+i*16).
__device__ __forceinline__ void async_load16(const bf16_t* g, bf16_t* lds) {
  __builtin_amdgcn_global_load_lds(
      (__attribute__((address_space(1))) uint32_t*)(g),
      (__attribute__((address_space(3))) uint32_t*)(lds),
      16, 0, 0);
}

// ---- Merged prep: W1 transpose (blocks 0-63), W2 transpose (64-191),
// ---- BN fold + w1last (192-195). -------------------------------------------
__global__ void prep_all_kernel(const float* __restrict__ W1, const float* __restrict__ W2,
                                const float* b1, const float* g1, const float* be1,
                                const float* m1, const float* v1,
                                const float* b2, const float* g2, const float* be2,
                                const float* m2, const float* v2,
                                bf16_t* __restrict__ W1T, bf16_t* __restrict__ W2T,
                                float* s1, float* t1, float* s2, float* t2,
                                float* w1last) {
  const int b = blockIdx.x;
  if (b < 192) {
    const float* src;
    bf16_t* dst;
    int R, C, bx, by;
    if (b < 64) { src = W1; dst = W1T; R = 256; C = 1024; bx = b & 15; by = b >> 4; }
    else        { src = W2; dst = W2T; R = 1024; C = 512; bx = (b - 64) & 7; by = (b - 64) >> 3; }
    __shared__ bf16_t tile[64][66];
    const int r0 = by * 64, c0 = bx * 64;
    const int tc = threadIdx.x & 63;
    const int tr4 = threadIdx.x >> 6;
#pragma unroll
    for (int i = 0; i < 16; ++i) {
      int r = i * 4 + tr4;
      tile[r][tc] = (bf16_t)src[(size_t)(r0 + r) * C + c0 + tc];  // coalesced read
    }
    __syncthreads();
#pragma unroll
    for (int i = 0; i < 16; ++i) {
      int rr = i * 4 + tr4;
      dst[(size_t)(c0 + rr) * R + r0 + tc] = tile[tc][rr];  // coalesced write
    }
  } else {
    int i = (b - 192) * 256 + threadIdx.x;
    if (i < 1024) {
      float s = g1[i] * rsqrtf(v1[i] + BN_EPS);
      s1[i] = s;
      t1[i] = be1[i] - m1[i] * s + b1[i] * s;  // bn(z+b1) = z*s + t
      w1last[i] = W1[256 * 1024 + i];          // conv-feature row (coalesced)
    }
    if (i < 512) {
      float s = g2[i] * rsqrtf(v2[i] + BN_EPS);
      s2[i] = s;
      t2[i] = be2[i] - m2[i] * s + b2[i] * s;
    }
  }
}

// ---- Prep: x -> bf16 + conv feature (mean>0); also zero the logit accum ----
__global__ void prep_x_kernel(const float* __restrict__ x, bf16_t* __restrict__ xb,
                              float* __restrict__ convf, float* __restrict__ outacc) {
  int lane = threadIdx.x & 63;
  int w = threadIdx.x >> 6;
  int row = blockIdx.x * 4 + w;
  const float4 v = *(const float4*)(x + (size_t)row * 256 + lane * 4);
  float s = v.x + v.y + v.z + v.w;
  bf16x4 o = {(bf16_t)v.x, (bf16_t)v.y, (bf16_t)v.z, (bf16_t)v.w};
  *(bf16x4*)(xb + (size_t)row * 256 + lane * 4) = o;
#pragma unroll
  for (int off = 32; off >= 1; off >>= 1) s += __shfl_down(s, off);
  if (lane == 0) convf[row] = (s > 0.0f) ? 1.0f : 0.0f;  // mean>0 <=> sum>0
  if (threadIdx.x < 4) outacc[blockIdx.x * 4 + threadIdx.x] = 0.0f;
}

// ---- Shared 256x128-tile GEMM core ------------------------------------------
// A [M x K] bf16 K-contig, BT [N x K] bf16 K-contig. Block: 256 thr = 4 waves;
// wave w computes rows [w*64, w*64+64) x all 128 cols. acc 4x8 f32x4.
// Per k-iter/wave: 6 async_load16, 12 ds_read_b128, 32 MFMA.
template <int K>
__device__ __forceinline__ void gemm_core_256x128(
    const bf16_t* __restrict__ A, const bf16_t* __restrict__ BT,
    int mTile, int nTile, bf16_t* As, bf16_t* Bs,
    int w, int lane, f32x4 (&acc)[4][8]) {
  const int l15 = lane & 15;
  const int quad = lane >> 4;
  const int sRow = lane >> 2;
  const int sCol = (lane & 3) * 8;
  const bf16_t* gA = A + (size_t)(mTile + w * 64 + sRow) * K + sCol;
  const bf16_t* gB = BT + (size_t)(nTile + w * 32 + sRow) * K + sCol;
  bf16_t* lA = As + (w * 64) * 32;
  bf16_t* lB = Bs + (w * 32) * 32;

  for (int k0 = 0; k0 < K; k0 += 32) {
    async_load16(gA + k0, lA);
    async_load16(gA + (size_t)16 * K + k0, lA + 16 * 32);
    async_load16(gA + (size_t)32 * K + k0, lA + 32 * 32);
    async_load16(gA + (size_t)48 * K + k0, lA + 48 * 32);
    async_load16(gB + k0, lB);
    async_load16(gB + (size_t)16 * K + k0, lB + 16 * 32);
    __syncthreads();  // drains vmcnt before barrier

    bf16x8 af[4], bfr[8];
#pragma unroll
    for (int t = 0; t < 4; ++t)
      af[t] = *(const bf16x8*)(As + (w * 64 + t * 16 + l15) * 32 + quad * 8);
#pragma unroll
    for (int t = 0; t < 8; ++t)
      bfr[t] = *(const bf16x8*)(Bs + (t * 16 + l15) * 32 + quad * 8);
#pragma unroll
    for (int ti = 0; ti < 4; ++ti)
#pragma unroll
      for (int tj = 0; tj < 8; ++tj)
        acc[ti][tj] = __builtin_amdgcn_mfma_f32_16x16x32_bf16(af[ti], bfr[tj], acc[ti][tj], 0, 0, 0);
    __syncthreads();
  }
}

// ---- GEMM1: h1 = relu(bn1(xb @ W1T^T + conv rank-1)), bf16 out --------------
// Grid 2048, XCD-aware: same-XCD (b&7) blocks sweep the 8 N-tiles of one
// M-tile consecutively -> A-tile L2-resident per XCD.
__global__ __launch_bounds__(256, 2) void gemm1_kernel(
    const bf16_t* __restrict__ A, const bf16_t* __restrict__ BT,
    const float* __restrict__ sN, const float* __restrict__ tN,
    const float* __restrict__ convf, const float* __restrict__ w1last,
    bf16_t* __restrict__ out) {
  constexpr int K = 256, N = 1024;
  __shared__ __align__(16) bf16_t As[256 * 32];
  __shared__ __align__(16) bf16_t Bs[128 * 32];

  const int b = blockIdx.x;
  const int mTile = ((b >> 6) * 8 + (b & 7)) * 256;  // 256 M-tiles
  const int nTile = ((b >> 3) & 7) * 128;            // 8 N-tiles

  const int tid = threadIdx.x;
  const int lane = tid & 63;
  const int w = tid >> 6;
  const int l15 = lane & 15;
  const int quad = lane >> 4;

  f32x4 acc[4][8];
#pragma unroll
  for (int i = 0; i < 4; ++i)
#pragma unroll
    for (int j = 0; j < 8; ++j) {
      f32x4 z = {0.f, 0.f, 0.f, 0.f};
      acc[i][j] = z;
    }

  gemm_core_256x128<K>(A, BT, mTile, nTile, As, Bs, w, lane, acc);

  // Epilogue: conv rank-1 + BN1 + ReLU -> bf16. C/D: col=l15, row=quad*4+reg.
  float sc[8], tc[8], wl[8];
#pragma unroll
  for (int tj = 0; tj < 8; ++tj) {
    int c = nTile + tj * 16 + l15;
    sc[tj] = sN[c];
    tc[tj] = tN[c];
    wl[tj] = w1last[c];
  }
#pragma unroll
  for (int ti = 0; ti < 4; ++ti)
#pragma unroll
    for (int r = 0; r < 4; ++r) {
      int row = mTile + w * 64 + ti * 16 + quad * 4 + r;
      float cf = convf[row];
      size_t base = (size_t)row * N + nTile;
#pragma unroll
      for (int tj = 0; tj < 8; ++tj) {
        float z = acc[ti][tj][r] + cf * wl[tj];
        z = fmaxf(z * sc[tj] + tc[tj], 0.f);
        out[base + tj * 16 + l15] = (bf16_t)z;
      }
    }
}

// ---- GEMM2 + head: partial logits via per-row atomicAdd ---------------------
// Grid 1024, XCD-aware swizzle (4 N-tiles per M-tile on one XCD).
__global__ __launch_bounds__(256, 2) void gemm2_head_kernel(
    const bf16_t* __restrict__ A, const bf16_t* __restrict__ BT,
    const float* __restrict__ sN, const float* __restrict__ tN,
    const float* __restrict__ W3, float* __restrict__ outacc) {
  constexpr int K = 1024;
  __shared__ __align__(16) bf16_t As[256 * 32];
  __shared__ __align__(16) bf16_t Bs[128 * 32];

  const int b = blockIdx.x;
  const int mTile = ((b >> 5) * 8 + (b & 7)) * 256;  // 256 M-tiles
  const int nTile = ((b >> 3) & 3) * 128;            // 4 N-tiles

  const int tid = threadIdx.x;
  const int lane = tid & 63;
  const int w = tid >> 6;
  const int l15 = lane & 15;
  const int quad = lane >> 4;

  f32x4 acc[4][8];
#pragma unroll
  for (int i = 0; i < 4; ++i)
#pragma unroll
    for (int j = 0; j < 8; ++j) {
      f32x4 z = {0.f, 0.f, 0.f, 0.f};
      acc[i][j] = z;
    }

  gemm_core_256x128<K>(A, BT, mTile, nTile, As, Bs, w, lane, acc);

  // Epilogue: per-row partial of relu(bn2)*W3 over this block's 128 cols.
  float sc[8], tc[8], w3c[8];
#pragma unroll
  for (int tj = 0; tj < 8; ++tj) {
    int c = nTile + tj * 16 + l15;
    sc[tj] = sN[c];
    tc[tj] = tN[c];
    w3c[tj] = W3[c];
  }
#pragma unroll
  for (int ti = 0; ti < 4; ++ti)
#pragma unroll
    for (int r = 0; r < 4; ++r) {
      float p = 0.f;
#pragma unroll
      for (int tj = 0; tj < 8; ++tj) {
        float z = fmaxf(acc[ti][tj][r] * sc[tj] + tc[tj], 0.f);
        p += z * w3c[tj];
      }
#pragma unroll
      for (int m = 1; m <= 8; m <<= 1) p += __shfl_xor(p, m);  // reduce 16 col-lanes
      if (l15 == 0)
        atomicAdd(outacc + mTile + w * 64 + ti * 16 + quad * 4 + r, p);
    }
}

// ---- Final sigmoid over accumulated logits ----------------------------------
__global__ void sigmoid_kernel(float* __restrict__ out, const float* __restrict__ b3) {
  int i = blockIdx.x * 256 + threadIdx.x;
  float z = out[i] + b3[0];
  out[i] = 1.0f / (1.0f + expf(-z));
}

extern "C" void kernel_launch(void* const* d_in, const int* in_sizes, int n_in,
                              void* d_out, int out_size, void* d_ws, size_t ws_size,
                              hipStream_t stream) {
  const float* x = (const float*)d_in[0];
  const float* W1 = (const float*)d_in[1];
  const float* b1 = (const float*)d_in[2];
  const float* g1 = (const float*)d_in[3];
  const float* be1 = (const float*)d_in[4];
  const float* m1 = (const float*)d_in[5];
  const float* v1 = (const float*)d_in[6];
  const float* W2 = (const float*)d_in[7];
  const float* b2 = (const float*)d_in[8];
  const float* g2 = (const float*)d_in[9];
  const float* be2 = (const float*)d_in[10];
  const float* m2 = (const float*)d_in[11];
  const float* v2 = (const float*)d_in[12];
  const float* W3 = (const float*)d_in[13];
  const float* b3 = (const float*)d_in[14];
  float* out = (float*)d_out;  // doubles as the fp32 logit accumulator

  char* p = (char*)d_ws;
  bf16_t* h1 = (bf16_t*)p;    p += (size_t)65536 * 1024 * 2;  // 128 MB
  bf16_t* xb = (bf16_t*)p;    p += (size_t)65536 * 256 * 2;   // 32 MB
  bf16_t* W1T = (bf16_t*)p;   p += (size_t)1024 * 256 * 2;
  bf16_t* W2T = (bf16_t*)p;   p += (size_t)512 * 1024 * 2;
  float* convf = (float*)p;   p += (size_t)65536 * 4;
  float* w1last = (float*)p;  p += 1024 * 4;
  float* s1 = (float*)p;      p += 1024 * 4;
  float* t1 = (float*)p;      p += 1024 * 4;
  float* s2 = (float*)p;      p += 512 * 4;
  float* t2 = (float*)p;      p += 512 * 4;

  prep_all_kernel<<<196, 256, 0, stream>>>(W1, W2, b1, g1, be1, m1, v1,
                                           b2, g2, be2, m2, v2,
                                           W1T, W2T, s1, t1, s2, t2, w1last);
  prep_x_kernel<<<16384, 256, 0, stream>>>(x, xb, convf, out);

  gemm1_kernel<<<2048, 256, 0, stream>>>(xb, W1T, s1, t1, convf, w1last, h1);
  gemm2_head_kernel<<<1024, 256, 0, stream>>>(h1, W2T, s2, t2, W3, out);

  sigmoid_kernel<<<256, 256, 0, stream>>>(out, b3);
}